// Round 12
// baseline (813.761 us; speedup 1.0000x reference)
//
#include <hip/hip_runtime.h>
#include <hip/hip_bf16.h>
#include <stdint.h>

// GCN 4-layer. R12: two-phase partitioned scatter replaces the 8-pass scan:
//   pass A (k_part): stream edges once, wave-ballot compaction -> 8 per-group
//     FIFOs (edge packed as dstLocal<<17|src, 31 bits).
//   pass B (k_fill): group g=blockIdx&7 consumes its contiguous FIFO slice;
//     cnt-atomic + bucket store stay XCD-L2-local with no streaming pollution.
// gemm/agg kernels unchanged from R11 (swizzled H, MFMA, verified).

#define TPB 256
#define MAXDEG 64
#define NGRP 8

typedef unsigned int uint;
typedef _Float16 h8 __attribute__((ext_vector_type(8)));
typedef _Float16 h16 __attribute__((ext_vector_type(16)));
typedef float f4 __attribute__((ext_vector_type(4)));

// swizzled storage position for feature f in a 64-wide H row
__device__ __forceinline__ int swz(int f) {
    return ((f >> 3) & 3) * 16 + (f >> 5) * 8 + (f & 7);
}

__device__ __forceinline__ int grp_of(int d, int chunk, float invchunk) {
    int g = (int)((float)d * invchunk);
    if (d >= (g + 1) * chunk) ++g;
    else if (d < g * chunk) --g;
    return g;
}

// Pass A: partition edges into 8 group FIFOs (wave-compacted appends).
__global__ __launch_bounds__(TPB) void k_part(const int* __restrict__ src,
                                              const int* __restrict__ dst,
                                              uint* __restrict__ gctr,
                                              uint* __restrict__ fifo,
                                              int E, int chunk, float invchunk, int cap) {
    int tid = blockIdx.x * TPB + (int)threadIdx.x;
    int lane = threadIdx.x & 63;
    int tstride = gridDim.x * TPB;
    int nq = E >> 2;
    const int4* dst4 = (const int4*)dst;
    const int4* src4 = (const int4*)src;
    unsigned long long lmlt = (lane == 0) ? 0ull : ((~0ull) >> (64 - lane));
    for (int q = tid; q < nq; q += tstride) {
        int4 d = dst4[q];
        int4 s = src4[q];
        int dd[4] = {d.x, d.y, d.z, d.w};
        int ss[4] = {s.x, s.y, s.z, s.w};
        int gg[4];
#pragma unroll
        for (int u = 0; u < 4; ++u) gg[u] = grp_of(dd[u], chunk, invchunk);
        uint pos[4] = {0u, 0u, 0u, 0u};
#pragma unroll
        for (int g = 0; g < NGRP; ++g) {
            unsigned long long m0 = __ballot(gg[0] == g);
            unsigned long long m1 = __ballot(gg[1] == g);
            unsigned long long m2 = __ballot(gg[2] == g);
            unsigned long long m3 = __ballot(gg[3] == g);
            uint c0 = (uint)__popcll(m0), c1 = (uint)__popcll(m1);
            uint c2 = (uint)__popcll(m2), c3 = (uint)__popcll(m3);
            uint total = c0 + c1 + c2 + c3;
            uint base = 0;
            if (lane == 0 && total) base = atomicAdd(&gctr[g], total);
            base = (uint)__shfl((int)base, 0, 64);
            if (gg[0] == g) pos[0] = base + (uint)__popcll(m0 & lmlt);
            if (gg[1] == g) pos[1] = base + c0 + (uint)__popcll(m1 & lmlt);
            if (gg[2] == g) pos[2] = base + c0 + c1 + (uint)__popcll(m2 & lmlt);
            if (gg[3] == g) pos[3] = base + c0 + c1 + c2 + (uint)__popcll(m3 & lmlt);
        }
#pragma unroll
        for (int u = 0; u < 4; ++u) {
            int g = gg[u];
            if (pos[u] < (uint)cap)
                fifo[(size_t)g * cap + pos[u]] =
                    ((uint)(dd[u] - g * chunk) << 17) | (uint)ss[u];
        }
    }
    // tail (E % 4)
    for (int e = (nq << 2) + tid; e < E; e += tstride) {
        int dv = dst[e], sv = src[e];
        int g = grp_of(dv, chunk, invchunk);
        uint p = atomicAdd(&gctr[g], 1u);
        if (p < (uint)cap)
            fifo[(size_t)g * cap + p] = ((uint)(dv - g * chunk) << 17) | (uint)sv;
    }
}

// Pass B: group-local bucket fill from contiguous FIFO slice.
__global__ __launch_bounds__(TPB) void k_fill(const uint* __restrict__ fifo,
                                              const uint* __restrict__ gctr,
                                              uint* __restrict__ cnt,
                                              int* __restrict__ bucket,
                                              int chunk, int cap) {
    int grp = blockIdx.x & (NGRP - 1);
    int bin = blockIdx.x >> 3;
    int bpg = gridDim.x >> 3;
    int n = (int)gctr[grp];
    if (n > cap) n = cap;
    const uint* f = fifo + (size_t)grp * cap;
    int tid = bin * TPB + (int)threadIdx.x;
    int tstr = bpg * TPB;
    int nq = n >> 2;
    const uint4* f4 = (const uint4*)f;
    int dbase = grp * chunk;
    for (int q = tid; q < nq; q += tstr) {
        uint4 v = f4[q];
        uint vv[4] = {v.x, v.y, v.z, v.w};
        int dd[4], ss[4];
#pragma unroll
        for (int u = 0; u < 4; ++u) { dd[u] = dbase + (int)(vv[u] >> 17); ss[u] = (int)(vv[u] & 0x1FFFFu); }
        uint pp[4];
#pragma unroll
        for (int u = 0; u < 4; ++u) pp[u] = atomicAdd(&cnt[dd[u]], 1u);
#pragma unroll
        for (int u = 0; u < 4; ++u)
            if (pp[u] < MAXDEG) bucket[(size_t)dd[u] * MAXDEG + (int)pp[u]] = ss[u];
    }
    for (int e = (nq << 2) + tid; e < n; e += tstr) {
        uint v = f[e];
        int dv = dbase + (int)(v >> 17);
        int sv = (int)(v & 0x1FFFFu);
        uint p = atomicAdd(&cnt[dv], 1u);
        if (p < MAXDEG) bucket[(size_t)dv * MAXDEG + (int)p] = sv;
    }
}

// Layer-1 GEMM via MFMA: H = fp16_swz((X @ W1) * dinv), K=128, FOUT=64. (R11)
__global__ __launch_bounds__(TPB) void k_gemm_mfma128(const float* __restrict__ X,
                                                      const float* __restrict__ W,
                                                      const uint* __restrict__ cnt,
                                                      _Float16* __restrict__ H,
                                                      int ngrp16, int nwaves, int n) {
    const int lane = threadIdx.x & 63;
    const int wid = blockIdx.x * (TPB / 64) + (threadIdx.x >> 6);
    const int nrow = lane & 15;
    const int kgrp = lane >> 4;

    h8 Bf[4][4];
#pragma unroll
    for (int kb = 0; kb < 4; ++kb)
#pragma unroll
        for (int j = 0; j < 8; ++j) {
            int k = kb * 32 + kgrp * 8 + j;
#pragma unroll
            for (int cb = 0; cb < 4; ++cb)
                Bf[kb][cb][j] = (_Float16)W[k * 64 + cb * 16 + nrow];
        }

    for (int g = wid; g < ngrp16; g += nwaves) {
        const int base = g * 16;
        int arow = base + nrow; if (arow >= n) arow = n - 1;
        const float* xr = X + (size_t)arow * 128;
        h8 A[4];
#pragma unroll
        for (int kb = 0; kb < 4; ++kb) {
            f4 lo = *(const f4*)(xr + kb * 32 + kgrp * 8);
            f4 hi = *(const f4*)(xr + kb * 32 + kgrp * 8 + 4);
#pragma unroll
            for (int j = 0; j < 4; ++j) { A[kb][j] = (_Float16)lo[j]; A[kb][4 + j] = (_Float16)hi[j]; }
        }
        f4 D[4];
#pragma unroll
        for (int cb = 0; cb < 4; ++cb) {
            f4 d = {0.f, 0.f, 0.f, 0.f};
#pragma unroll
            for (int kb = 0; kb < 4; ++kb)
                d = __builtin_amdgcn_mfma_f32_16x16x32_f16(A[kb], Bf[kb][cb], d, 0, 0, 0);
            D[cb] = d;
        }
#pragma unroll
        for (int r = 0; r < 4; ++r) {
            int onode = base + kgrp * 4 + r;
            if (onode < n) {
                float dio = rsqrtf((float)cnt[onode] + 1.0f);
#pragma unroll
                for (int cb = 0; cb < 4; ++cb)
                    H[(size_t)onode * 64 + swz(cb * 16 + nrow)] = (_Float16)(D[cb][r] * dio);
            }
        }
    }
}

// Fused agg + MFMA GEMM over 16-node groups; swizzled 32B per-lane rows. (R11)
template <int FOUT>
__global__ __launch_bounds__(TPB, 2) void k_agg_mfma(const _Float16* __restrict__ H,
                                                     const int* __restrict__ bucket,
                                                     const uint* __restrict__ cnt,
                                                     const float* __restrict__ b,
                                                     const float* __restrict__ W,
                                                     _Float16* __restrict__ Hout,
                                                     int ngrp16, int nwaves) {
    const int lane = threadIdx.x & 63;
    const int wid = blockIdx.x * (TPB / 64) + (threadIdx.x >> 6);
    const int nrow = lane & 15;
    const int kgrp = lane >> 4;
    const int kofs = kgrp * 16;
    constexpr int NCB = FOUT / 16;

    h8 Bf[2][NCB];
    float bias[16];
#pragma unroll
    for (int kb = 0; kb < 2; ++kb)
#pragma unroll
        for (int j = 0; j < 8; ++j) {
            int f = kb * 32 + kgrp * 8 + j;
            bias[kb * 8 + j] = b[f];
#pragma unroll
            for (int cb = 0; cb < NCB; ++cb)
                Bf[kb][cb][j] = (_Float16)W[f * FOUT + cb * 16 + nrow];
        }

    for (int g = wid; g < ngrp16; g += nwaves) {
        const int base = g * 16;
        const int node = base + nrow;
        const int cc = (int)cnt[node];
        const int cn = (cc < MAXDEG) ? cc : MAXDEG;

        float acc[16];
        {
            h16 sv = *(const h16*)(H + (size_t)node * 64 + kofs);
#pragma unroll
            for (int j = 0; j < 16; ++j) acc[j] = (float)sv[j];
        }
        const int* eb = bucket + (size_t)node * MAXDEG;
        int t = 0;
        for (; t + 4 <= cn; t += 4) {
            int i0 = eb[t], i1 = eb[t + 1], i2 = eb[t + 2], i3 = eb[t + 3];
            h16 v0 = *(const h16*)(H + (size_t)i0 * 64 + kofs);
            h16 v1 = *(const h16*)(H + (size_t)i1 * 64 + kofs);
            h16 v2 = *(const h16*)(H + (size_t)i2 * 64 + kofs);
            h16 v3 = *(const h16*)(H + (size_t)i3 * 64 + kofs);
#pragma unroll
            for (int j = 0; j < 16; ++j)
                acc[j] += ((float)v0[j] + (float)v1[j]) + ((float)v2[j] + (float)v3[j]);
        }
        if (t + 2 <= cn) {
            int i0 = eb[t], i1 = eb[t + 1];
            h16 v0 = *(const h16*)(H + (size_t)i0 * 64 + kofs);
            h16 v1 = *(const h16*)(H + (size_t)i1 * 64 + kofs);
#pragma unroll
            for (int j = 0; j < 16; ++j) acc[j] += (float)v0[j] + (float)v1[j];
            t += 2;
        }
        if (t < cn) {
            h16 v0 = *(const h16*)(H + (size_t)eb[t] * 64 + kofs);
#pragma unroll
            for (int j = 0; j < 16; ++j) acc[j] += (float)v0[j];
        }

        float di = rsqrtf((float)cc + 1.0f);
        h8 A0, A1;
#pragma unroll
        for (int j = 0; j < 8; ++j) {
            A0[j] = (_Float16)fmaxf(fmaf(di, acc[j], bias[j]), 0.f);
            A1[j] = (_Float16)fmaxf(fmaf(di, acc[8 + j], bias[8 + j]), 0.f);
        }

        f4 D[NCB];
#pragma unroll
        for (int cb = 0; cb < NCB; ++cb) {
            f4 d = {0.f, 0.f, 0.f, 0.f};
            d = __builtin_amdgcn_mfma_f32_16x16x32_f16(A0, Bf[0][cb], d, 0, 0, 0);
            d = __builtin_amdgcn_mfma_f32_16x16x32_f16(A1, Bf[1][cb], d, 0, 0, 0);
            D[cb] = d;
        }
#pragma unroll
        for (int r = 0; r < 4; ++r) {
            int onode = base + kgrp * 4 + r;
            float dio = rsqrtf((float)cnt[onode] + 1.0f);
#pragma unroll
            for (int cb = 0; cb < NCB; ++cb) {
                int f = cb * 16 + nrow;
                int p = (FOUT == 64) ? swz(f) : f;
                Hout[(size_t)onode * FOUT + p] = (_Float16)(D[cb][r] * dio);
            }
        }
    }
}

// Final aggregation on fp16 F=16 rows (linear layout): f32 out, no relu. (R11)
__global__ __launch_bounds__(TPB) void k_agg16(const _Float16* __restrict__ H,
                                               const int* __restrict__ bucket,
                                               const uint* __restrict__ cnt,
                                               const float* __restrict__ b,
                                               float* __restrict__ Out, int n) {
    int tid = blockIdx.x * TPB + threadIdx.x;
    int node = tid >> 4;
    int feat = tid & 15;
    if (node >= n) return;
    float s0 = (float)H[(size_t)node * 16 + feat];
    float s1 = 0.f, s2 = 0.f, s3 = 0.f, s4 = 0.f, s5 = 0.f, s6 = 0.f, s7 = 0.f;
    const int craw = (int)cnt[node];
    const int cn = (craw < MAXDEG) ? craw : MAXDEG;
    const int* eb = bucket + (size_t)node * MAXDEG;
    int t = 0;
    for (; t + 8 <= cn; t += 8) {
        int i0 = eb[t],     i1 = eb[t + 1], i2 = eb[t + 2], i3 = eb[t + 3];
        int i4 = eb[t + 4], i5 = eb[t + 5], i6 = eb[t + 6], i7 = eb[t + 7];
        float v0 = (float)H[(size_t)i0 * 16 + feat];
        float v1 = (float)H[(size_t)i1 * 16 + feat];
        float v2 = (float)H[(size_t)i2 * 16 + feat];
        float v3 = (float)H[(size_t)i3 * 16 + feat];
        float v4 = (float)H[(size_t)i4 * 16 + feat];
        float v5 = (float)H[(size_t)i5 * 16 + feat];
        float v6 = (float)H[(size_t)i6 * 16 + feat];
        float v7 = (float)H[(size_t)i7 * 16 + feat];
        s0 += v0; s1 += v1; s2 += v2; s3 += v3;
        s4 += v4; s5 += v5; s6 += v6; s7 += v7;
    }
    if (t + 4 <= cn) {
        int i0 = eb[t], i1 = eb[t + 1], i2 = eb[t + 2], i3 = eb[t + 3];
        s0 += (float)H[(size_t)i0 * 16 + feat];
        s1 += (float)H[(size_t)i1 * 16 + feat];
        s2 += (float)H[(size_t)i2 * 16 + feat];
        s3 += (float)H[(size_t)i3 * 16 + feat];
        t += 4;
    }
    if (t + 2 <= cn) {
        int i0 = eb[t], i1 = eb[t + 1];
        s0 += (float)H[(size_t)i0 * 16 + feat];
        s1 += (float)H[(size_t)i1 * 16 + feat];
        t += 2;
    }
    if (t < cn) s0 += (float)H[(size_t)eb[t] * 16 + feat];
    float di = rsqrtf((float)craw + 1.0f);
    float s = ((s0 + s1) + (s2 + s3)) + ((s4 + s5) + (s6 + s7));
    Out[(size_t)node * 16 + feat] = di * s + b[feat];
}

static inline size_t align256(size_t x) { return (x + 255) & ~(size_t)255; }

extern "C" void kernel_launch(void* const* d_in, const int* in_sizes, int n_in,
                              void* d_out, int out_size, void* d_ws, size_t ws_size,
                              hipStream_t stream) {
    const float* x  = (const float*)d_in[0];
    const int* ei   = (const int*)d_in[1];
    const float* W1 = (const float*)d_in[2];
    const float* b1 = (const float*)d_in[3];
    const float* W2 = (const float*)d_in[4];
    const float* b2 = (const float*)d_in[5];
    const float* W3 = (const float*)d_in[6];
    const float* b3 = (const float*)d_in[7];
    const float* W4 = (const float*)d_in[8];
    const float* b4 = (const float*)d_in[9];
    float* out = (float*)d_out;

    const int N = in_sizes[0] / 128;
    const int E = in_sizes[1] / 2;
    const int* src = ei;
    const int* dst = ei + E;

    const int chunk = (N + NGRP - 1) / NGRP;
    const float invchunk = 1.0f / (float)chunk;
    const int cap = E / NGRP + 8192;

    // workspace: cnt | gctr (zeroed) | bucket | fifo | hA | hB
    char* p = (char*)d_ws;
    size_t off = 0;
    uint* cnt = (uint*)(p + off); off += align256((size_t)N * 4);
    uint* gctr = (uint*)(p + off); off += 256;
    size_t zero_bytes = off;
    int* bucket = (int*)(p + off); off += align256((size_t)N * MAXDEG * 4);
    uint* fifo = (uint*)(p + off); off += align256((size_t)NGRP * cap * 4);
    _Float16* hA = (_Float16*)(p + off); off += align256((size_t)N * 64 * 2);
    _Float16* hB = (_Float16*)(p + off); off += align256((size_t)N * 64 * 2);
    (void)ws_size;

    hipMemsetAsync(d_ws, 0, zero_bytes, stream);

    k_part<<<1024, TPB, 0, stream>>>(src, dst, gctr, fifo, E, chunk, invchunk, cap);
    k_fill<<<2048, TPB, 0, stream>>>(fifo, gctr, cnt, bucket, chunk, cap);

    const int ngrp16 = (N + 15) / 16;            // 6250 for N=100000
    const int NBLK_M = (ngrp16 + (TPB / 64) - 1) / (TPB / 64);   // 1563
    const int NWAVES_M = NBLK_M * (TPB / 64);

    k_gemm_mfma128<<<NBLK_M, TPB, 0, stream>>>(x, W1, cnt, hA, ngrp16, NWAVES_M, N);
    k_agg_mfma<64><<<NBLK_M, TPB, 0, stream>>>(hA, bucket, cnt, b1, W2, hB, ngrp16, NWAVES_M);
    k_agg_mfma<64><<<NBLK_M, TPB, 0, stream>>>(hB, bucket, cnt, b2, W3, hA, ngrp16, NWAVES_M);
    k_agg_mfma<16><<<NBLK_M, TPB, 0, stream>>>(hA, bucket, cnt, b3, W4, hB, ngrp16, NWAVES_M);
    int gAgg16 = (N * 16 + TPB - 1) / TPB;
    k_agg16<<<gAgg16, TPB, 0, stream>>>(hB, bucket, cnt, b4, out, N);
}

// Round 13
// 248.698 us; speedup vs baseline: 3.2721x; 3.2721x over previous
//
#include <hip/hip_runtime.h>
#include <hip/hip_bf16.h>
#include <stdint.h>

// GCN 4-layer. R13: two-phase scatter with BLOCK-LOCAL reservations.
// R12's k_part died on 50K same-address global atomics (572us). Now:
//   k_part: 256 blocks, each owns E/256 edges + fixed per-group slabs
//           (cap 1536, overlaid on hB); positions via LDS atomics only.
//   k_fill: block (bid>>3, bid&7) consumes one slab; cnt/bucket writes
//           XCD-local (R11 scheme); reads 6.5MB vs R11's 51MB redundancy.
// gemm/agg kernels unchanged from R11 (swizzled H, MFMA, verified).

#define TPB 256
#define MAXDEG 64
#define NGRP 8
#define NBLK_P 256
#define SLABCAP 1536
#define OVCAP 65536

typedef unsigned int uint;
typedef _Float16 h8 __attribute__((ext_vector_type(8)));
typedef _Float16 h16 __attribute__((ext_vector_type(16)));
typedef float f4 __attribute__((ext_vector_type(4)));

// swizzled storage position for feature f in a 64-wide H row
__device__ __forceinline__ int swz(int f) {
    return ((f >> 3) & 3) * 16 + (f >> 5) * 8 + (f & 7);
}

__device__ __forceinline__ int grp_of(int d, int chunk, float invchunk) {
    int g = (int)((float)d * invchunk);
    if (d >= (g + 1) * chunk) ++g;
    else if (d < g * chunk) --g;
    return g;
}

// Pass A: per-block slab partition. LDS counters only; no global atomics
// (except never-taken overflow path).
__global__ __launch_bounds__(TPB) void k_part(const int* __restrict__ src,
                                              const int* __restrict__ dst,
                                              uint* __restrict__ pcount,
                                              uint* __restrict__ ovcnt,
                                              int* __restrict__ ovbuf,
                                              uint* __restrict__ slab,
                                              int E, int chunk, float invchunk,
                                              int range) {
    __shared__ uint lcnt[NGRP];
    if (threadIdx.x < NGRP) lcnt[threadIdx.x] = 0;
    __syncthreads();
    const int e0 = blockIdx.x * range;
    const int e1 = (e0 + range < E) ? e0 + range : E;
    for (int e = e0 + (int)threadIdx.x; e < e1; e += TPB) {
        int d = dst[e];
        int s = src[e];
        int g = grp_of(d, chunk, invchunk);
        uint pos = atomicAdd(&lcnt[g], 1u);
        uint val = ((uint)(d - g * chunk) << 17) | (uint)s;
        if (pos < SLABCAP) {
            slab[((size_t)blockIdx.x * NGRP + g) * SLABCAP + pos] = val;
        } else {
            uint p = atomicAdd(ovcnt, 1u);
            if (p < OVCAP) { ovbuf[2 * p] = d; ovbuf[2 * p + 1] = s; }
        }
    }
    __syncthreads();
    if (threadIdx.x < NGRP) {
        uint c = lcnt[threadIdx.x];
        pcount[blockIdx.x * NGRP + threadIdx.x] = (c < SLABCAP) ? c : SLABCAP;
    }
}

// Pass B: block (bid>>3, bid&7) fills from its slab; XCD-local cnt/bucket.
__global__ __launch_bounds__(TPB) void k_fill(const uint* __restrict__ slab,
                                              const uint* __restrict__ pcount,
                                              const uint* __restrict__ ovcnt,
                                              const int* __restrict__ ovbuf,
                                              uint* __restrict__ cnt,
                                              int* __restrict__ bucket,
                                              int chunk) {
    const int grp = blockIdx.x & (NGRP - 1);
    const int blk = blockIdx.x >> 3;
    const int n = (int)pcount[blk * NGRP + grp];
    const uint* s = slab + ((size_t)blk * NGRP + grp) * SLABCAP;
    const int dbase = grp * chunk;
    int e = (int)threadIdx.x;
    // 2-wide pipeline over the slab
    for (; e + TPB < n; e += 2 * TPB) {
        uint v0 = s[e];
        uint v1 = s[e + TPB];
        int d0 = dbase + (int)(v0 >> 17), s0 = (int)(v0 & 0x1FFFFu);
        int d1 = dbase + (int)(v1 >> 17), s1 = (int)(v1 & 0x1FFFFu);
        uint p0 = atomicAdd(&cnt[d0], 1u);
        uint p1 = atomicAdd(&cnt[d1], 1u);
        if (p0 < MAXDEG) bucket[(size_t)d0 * MAXDEG + (int)p0] = s0;
        if (p1 < MAXDEG) bucket[(size_t)d1 * MAXDEG + (int)p1] = s1;
    }
    if (e < n) {
        uint v = s[e];
        int d = dbase + (int)(v >> 17), sv = (int)(v & 0x1FFFFu);
        uint p = atomicAdd(&cnt[d], 1u);
        if (p < MAXDEG) bucket[(size_t)d * MAXDEG + (int)p] = sv;
    }
    // overflow (expected empty): blk==0 blocks scan, filtered by group
    if (blk == 0) {
        uint on = *ovcnt;
        if (on > OVCAP) on = OVCAP;
        for (uint i = threadIdx.x; i < on; i += TPB) {
            int d = ovbuf[2 * i];
            if (d >= dbase && d < dbase + chunk) {
                int sv = ovbuf[2 * i + 1];
                uint p = atomicAdd(&cnt[d], 1u);
                if (p < MAXDEG) bucket[(size_t)d * MAXDEG + (int)p] = sv;
            }
        }
    }
}

// Layer-1 GEMM via MFMA: H = fp16_swz((X @ W1) * dinv), K=128, FOUT=64. (R11)
__global__ __launch_bounds__(TPB) void k_gemm_mfma128(const float* __restrict__ X,
                                                      const float* __restrict__ W,
                                                      const uint* __restrict__ cnt,
                                                      _Float16* __restrict__ H,
                                                      int ngrp16, int nwaves, int n) {
    const int lane = threadIdx.x & 63;
    const int wid = blockIdx.x * (TPB / 64) + (threadIdx.x >> 6);
    const int nrow = lane & 15;
    const int kgrp = lane >> 4;

    h8 Bf[4][4];
#pragma unroll
    for (int kb = 0; kb < 4; ++kb)
#pragma unroll
        for (int j = 0; j < 8; ++j) {
            int k = kb * 32 + kgrp * 8 + j;
#pragma unroll
            for (int cb = 0; cb < 4; ++cb)
                Bf[kb][cb][j] = (_Float16)W[k * 64 + cb * 16 + nrow];
        }

    for (int g = wid; g < ngrp16; g += nwaves) {
        const int base = g * 16;
        int arow = base + nrow; if (arow >= n) arow = n - 1;
        const float* xr = X + (size_t)arow * 128;
        h8 A[4];
#pragma unroll
        for (int kb = 0; kb < 4; ++kb) {
            f4 lo = *(const f4*)(xr + kb * 32 + kgrp * 8);
            f4 hi = *(const f4*)(xr + kb * 32 + kgrp * 8 + 4);
#pragma unroll
            for (int j = 0; j < 4; ++j) { A[kb][j] = (_Float16)lo[j]; A[kb][4 + j] = (_Float16)hi[j]; }
        }
        f4 D[4];
#pragma unroll
        for (int cb = 0; cb < 4; ++cb) {
            f4 d = {0.f, 0.f, 0.f, 0.f};
#pragma unroll
            for (int kb = 0; kb < 4; ++kb)
                d = __builtin_amdgcn_mfma_f32_16x16x32_f16(A[kb], Bf[kb][cb], d, 0, 0, 0);
            D[cb] = d;
        }
#pragma unroll
        for (int r = 0; r < 4; ++r) {
            int onode = base + kgrp * 4 + r;
            if (onode < n) {
                float dio = rsqrtf((float)cnt[onode] + 1.0f);
#pragma unroll
                for (int cb = 0; cb < 4; ++cb)
                    H[(size_t)onode * 64 + swz(cb * 16 + nrow)] = (_Float16)(D[cb][r] * dio);
            }
        }
    }
}

// Fused agg + MFMA GEMM over 16-node groups; swizzled 32B per-lane rows. (R11)
template <int FOUT>
__global__ __launch_bounds__(TPB, 2) void k_agg_mfma(const _Float16* __restrict__ H,
                                                     const int* __restrict__ bucket,
                                                     const uint* __restrict__ cnt,
                                                     const float* __restrict__ b,
                                                     const float* __restrict__ W,
                                                     _Float16* __restrict__ Hout,
                                                     int ngrp16, int nwaves) {
    const int lane = threadIdx.x & 63;
    const int wid = blockIdx.x * (TPB / 64) + (threadIdx.x >> 6);
    const int nrow = lane & 15;
    const int kgrp = lane >> 4;
    const int kofs = kgrp * 16;
    constexpr int NCB = FOUT / 16;

    h8 Bf[2][NCB];
    float bias[16];
#pragma unroll
    for (int kb = 0; kb < 2; ++kb)
#pragma unroll
        for (int j = 0; j < 8; ++j) {
            int f = kb * 32 + kgrp * 8 + j;
            bias[kb * 8 + j] = b[f];
#pragma unroll
            for (int cb = 0; cb < NCB; ++cb)
                Bf[kb][cb][j] = (_Float16)W[f * FOUT + cb * 16 + nrow];
        }

    for (int g = wid; g < ngrp16; g += nwaves) {
        const int base = g * 16;
        const int node = base + nrow;
        const int cc = (int)cnt[node];
        const int cn = (cc < MAXDEG) ? cc : MAXDEG;

        float acc[16];
        {
            h16 sv = *(const h16*)(H + (size_t)node * 64 + kofs);
#pragma unroll
            for (int j = 0; j < 16; ++j) acc[j] = (float)sv[j];
        }
        const int* eb = bucket + (size_t)node * MAXDEG;
        int t = 0;
        for (; t + 4 <= cn; t += 4) {
            int i0 = eb[t], i1 = eb[t + 1], i2 = eb[t + 2], i3 = eb[t + 3];
            h16 v0 = *(const h16*)(H + (size_t)i0 * 64 + kofs);
            h16 v1 = *(const h16*)(H + (size_t)i1 * 64 + kofs);
            h16 v2 = *(const h16*)(H + (size_t)i2 * 64 + kofs);
            h16 v3 = *(const h16*)(H + (size_t)i3 * 64 + kofs);
#pragma unroll
            for (int j = 0; j < 16; ++j)
                acc[j] += ((float)v0[j] + (float)v1[j]) + ((float)v2[j] + (float)v3[j]);
        }
        if (t + 2 <= cn) {
            int i0 = eb[t], i1 = eb[t + 1];
            h16 v0 = *(const h16*)(H + (size_t)i0 * 64 + kofs);
            h16 v1 = *(const h16*)(H + (size_t)i1 * 64 + kofs);
#pragma unroll
            for (int j = 0; j < 16; ++j) acc[j] += (float)v0[j] + (float)v1[j];
            t += 2;
        }
        if (t < cn) {
            h16 v0 = *(const h16*)(H + (size_t)eb[t] * 64 + kofs);
#pragma unroll
            for (int j = 0; j < 16; ++j) acc[j] += (float)v0[j];
        }

        float di = rsqrtf((float)cc + 1.0f);
        h8 A0, A1;
#pragma unroll
        for (int j = 0; j < 8; ++j) {
            A0[j] = (_Float16)fmaxf(fmaf(di, acc[j], bias[j]), 0.f);
            A1[j] = (_Float16)fmaxf(fmaf(di, acc[8 + j], bias[8 + j]), 0.f);
        }

        f4 D[NCB];
#pragma unroll
        for (int cb = 0; cb < NCB; ++cb) {
            f4 d = {0.f, 0.f, 0.f, 0.f};
            d = __builtin_amdgcn_mfma_f32_16x16x32_f16(A0, Bf[0][cb], d, 0, 0, 0);
            d = __builtin_amdgcn_mfma_f32_16x16x32_f16(A1, Bf[1][cb], d, 0, 0, 0);
            D[cb] = d;
        }
#pragma unroll
        for (int r = 0; r < 4; ++r) {
            int onode = base + kgrp * 4 + r;
            float dio = rsqrtf((float)cnt[onode] + 1.0f);
#pragma unroll
            for (int cb = 0; cb < NCB; ++cb) {
                int f = cb * 16 + nrow;
                int p = (FOUT == 64) ? swz(f) : f;
                Hout[(size_t)onode * FOUT + p] = (_Float16)(D[cb][r] * dio);
            }
        }
    }
}

// Final aggregation on fp16 F=16 rows (linear layout): f32 out, no relu. (R11)
__global__ __launch_bounds__(TPB) void k_agg16(const _Float16* __restrict__ H,
                                               const int* __restrict__ bucket,
                                               const uint* __restrict__ cnt,
                                               const float* __restrict__ b,
                                               float* __restrict__ Out, int n) {
    int tid = blockIdx.x * TPB + threadIdx.x;
    int node = tid >> 4;
    int feat = tid & 15;
    if (node >= n) return;
    float s0 = (float)H[(size_t)node * 16 + feat];
    float s1 = 0.f, s2 = 0.f, s3 = 0.f, s4 = 0.f, s5 = 0.f, s6 = 0.f, s7 = 0.f;
    const int craw = (int)cnt[node];
    const int cn = (craw < MAXDEG) ? craw : MAXDEG;
    const int* eb = bucket + (size_t)node * MAXDEG;
    int t = 0;
    for (; t + 8 <= cn; t += 8) {
        int i0 = eb[t],     i1 = eb[t + 1], i2 = eb[t + 2], i3 = eb[t + 3];
        int i4 = eb[t + 4], i5 = eb[t + 5], i6 = eb[t + 6], i7 = eb[t + 7];
        float v0 = (float)H[(size_t)i0 * 16 + feat];
        float v1 = (float)H[(size_t)i1 * 16 + feat];
        float v2 = (float)H[(size_t)i2 * 16 + feat];
        float v3 = (float)H[(size_t)i3 * 16 + feat];
        float v4 = (float)H[(size_t)i4 * 16 + feat];
        float v5 = (float)H[(size_t)i5 * 16 + feat];
        float v6 = (float)H[(size_t)i6 * 16 + feat];
        float v7 = (float)H[(size_t)i7 * 16 + feat];
        s0 += v0; s1 += v1; s2 += v2; s3 += v3;
        s4 += v4; s5 += v5; s6 += v6; s7 += v7;
    }
    if (t + 4 <= cn) {
        int i0 = eb[t], i1 = eb[t + 1], i2 = eb[t + 2], i3 = eb[t + 3];
        s0 += (float)H[(size_t)i0 * 16 + feat];
        s1 += (float)H[(size_t)i1 * 16 + feat];
        s2 += (float)H[(size_t)i2 * 16 + feat];
        s3 += (float)H[(size_t)i3 * 16 + feat];
        t += 4;
    }
    if (t + 2 <= cn) {
        int i0 = eb[t], i1 = eb[t + 1];
        s0 += (float)H[(size_t)i0 * 16 + feat];
        s1 += (float)H[(size_t)i1 * 16 + feat];
        t += 2;
    }
    if (t < cn) s0 += (float)H[(size_t)eb[t] * 16 + feat];
    float di = rsqrtf((float)craw + 1.0f);
    float s = ((s0 + s1) + (s2 + s3)) + ((s4 + s5) + (s6 + s7));
    Out[(size_t)node * 16 + feat] = di * s + b[feat];
}

static inline size_t align256(size_t x) { return (x + 255) & ~(size_t)255; }

extern "C" void kernel_launch(void* const* d_in, const int* in_sizes, int n_in,
                              void* d_out, int out_size, void* d_ws, size_t ws_size,
                              hipStream_t stream) {
    const float* x  = (const float*)d_in[0];
    const int* ei   = (const int*)d_in[1];
    const float* W1 = (const float*)d_in[2];
    const float* b1 = (const float*)d_in[3];
    const float* W2 = (const float*)d_in[4];
    const float* b2 = (const float*)d_in[5];
    const float* W3 = (const float*)d_in[6];
    const float* b3 = (const float*)d_in[7];
    const float* W4 = (const float*)d_in[8];
    const float* b4 = (const float*)d_in[9];
    float* out = (float*)d_out;

    const int N = in_sizes[0] / 128;
    const int E = in_sizes[1] / 2;
    const int* src = ei;
    const int* dst = ei + E;

    const int chunk = (N + NGRP - 1) / NGRP;
    const float invchunk = 1.0f / (float)chunk;
    const int range = (E + NBLK_P - 1) / NBLK_P;

    // workspace: cnt | pcount | ovcnt (zeroed) | bucket | ovbuf | hA | hB
    // slab (12.6MB) overlays hB (12.8MB) — hB unused until layer-2 output.
    char* p = (char*)d_ws;
    size_t off = 0;
    uint* cnt = (uint*)(p + off); off += align256((size_t)N * 4);
    uint* pcount = (uint*)(p + off); off += align256((size_t)NBLK_P * NGRP * 4);
    uint* ovcnt = (uint*)(p + off); off += 256;
    size_t zero_bytes = off;
    int* bucket = (int*)(p + off); off += align256((size_t)N * MAXDEG * 4);
    int* ovbuf = (int*)(p + off); off += align256((size_t)OVCAP * 8);
    _Float16* hA = (_Float16*)(p + off); off += align256((size_t)N * 64 * 2);
    _Float16* hB = (_Float16*)(p + off); off += align256((size_t)N * 64 * 2);
    uint* slab = (uint*)hB;   // overlay
    (void)ws_size;

    hipMemsetAsync(d_ws, 0, zero_bytes, stream);

    k_part<<<NBLK_P, TPB, 0, stream>>>(src, dst, pcount, ovcnt, ovbuf, slab,
                                       E, chunk, invchunk, range);
    k_fill<<<NBLK_P * NGRP, TPB, 0, stream>>>(slab, pcount, ovcnt, ovbuf,
                                              cnt, bucket, chunk);

    const int ngrp16 = (N + 15) / 16;            // 6250 for N=100000
    const int NBLK_M = (ngrp16 + (TPB / 64) - 1) / (TPB / 64);   // 1563
    const int NWAVES_M = NBLK_M * (TPB / 64);

    k_gemm_mfma128<<<NBLK_M, TPB, 0, stream>>>(x, W1, cnt, hA, ngrp16, NWAVES_M, N);
    k_agg_mfma<64><<<NBLK_M, TPB, 0, stream>>>(hA, bucket, cnt, b1, W2, hB, ngrp16, NWAVES_M);
    k_agg_mfma<64><<<NBLK_M, TPB, 0, stream>>>(hB, bucket, cnt, b2, W3, hA, ngrp16, NWAVES_M);
    k_agg_mfma<16><<<NBLK_M, TPB, 0, stream>>>(hA, bucket, cnt, b3, W4, hB, ngrp16, NWAVES_M);
    int gAgg16 = (N * 16 + TPB - 1) / TPB;
    k_agg16<<<gAgg16, TPB, 0, stream>>>(hB, bucket, cnt, b4, out, N);
}